// Round 12
// baseline (57.356 us; speedup 1.0000x reference)
//
#include <hip/hip_runtime.h>

// Shapes fixed by the benchmark's setup_inputs().
constexpr int T_DIM       = 16;
constexpr int TOK         = 16384;
constexpr int E_DIM       = 128;
constexpr int N_NODE_C    = 8192;
constexpr int NUM_NODES_C = 50000;
constexpr int COMP_LEN_C  = 64;
constexpr int MAX_LEN_C   = 782;
constexpr int COMP_DIM_C  = 32;
constexpr float EPS_F     = 1e-5f;

constexpr int D2 = COMP_LEN_C * COMP_DIM_C;  // 2048

// d_ws layout: W8 (3.2MB) | Agg (128KB) | pooled (16MB). memset covers W8+Agg.
constexpr size_t W8_BYTES  = (size_t)NUM_NODES_C * COMP_LEN_C;    // 3,200,000
constexpr size_t AGG_OFF   = 3211264;
constexpr size_t AGG_BYTES = (size_t)T_DIM * D2 * sizeof(float);  // 131,072
constexpr size_t ZERO_BYTES = AGG_OFF + AGG_BYTES;
constexpr size_t POOL_OFF  = AGG_OFF + AGG_BYTES;                 // 3,342,336
// pooled: [T_DIM][N_NODE][32] floats = 16 MB

// --- Build W[n][c] (uint8 counts) via byte-atomics into u32 words. 256 WGs.
__global__ void build_w8_kernel(const int* __restrict__ sidx, unsigned* __restrict__ W8w) {
  const int c  = blockIdx.x >> 2;
  const int jc = blockIdx.x & 3;
  const int j  = jc * 196 + threadIdx.x;
  if (j < MAX_LEN_C && threadIdx.x < 196) {
    int n = sidx[c * MAX_LEN_C + j];
    int byteoff = n * COMP_LEN_C + c;
    atomicAdd(&W8w[byteoff >> 2], 1u << (8 * (byteoff & 3)));
  }
}

// --- Kernel A: pure stream LN1 + pool-of-4. PERFECTLY dense loads/stores.
// Lane l handles row r0+(l>>5), group g=l&31 (elems 4g..4g+3, one pool group).
// Wave load = 64 consecutive float4 = 1KB dense; store = 64 consecutive floats.
// 2048 blocks x 256 thr; each wave: 16 rows as 8 iterations of 2, all 8 loads
// issued upfront (2KB/wave in flight).
__global__ __launch_bounds__(256, 4) void stream_ln_pool(
    const float* __restrict__ x, const float* __restrict__ g1, const float* __restrict__ b1,
    float* __restrict__ pooled) {
  const int t     = blockIdx.x >> 7;            // /128
  const int chunk = blockIdx.x & 127;
  const int lane  = threadIdx.x & 63;
  const int wave  = threadIdx.x >> 6;           // 4 waves
  const int g     = lane & 31;
  const int half  = lane >> 5;

  // per-lane LN constants for its 4-elem group
  const float4 gv = *reinterpret_cast<const float4*>(g1 + g * 4);
  const float4 bv = *reinterpret_cast<const float4*>(b1 + g * 4);
  const float sg = gv.x + gv.y + gv.z + gv.w;
  const float sb = bv.x + bv.y + bv.z + bv.w;

  const int r0 = chunk * 64 + wave * 16;        // 16 rows per wave
  const float4* xv = reinterpret_cast<const float4*>(x + (size_t)t * TOK * E_DIM);
  float* pt = pooled + ((size_t)t * N_NODE_C + r0) * COMP_DIM_C;

  // all 8 iteration loads upfront: iter i covers rows r0+2i, r0+2i+1
  float4 xd[8];
#pragma unroll
  for (int i = 0; i < 8; ++i)
    xd[i] = xv[(size_t)(r0 + 2 * i) * 32 + lane];   // 64 consecutive float4

#pragma unroll
  for (int i = 0; i < 8; ++i) {
    const float4 a = xd[i];
    float s  = (a.x + a.y) + (a.z + a.w);
    float ss = a.x * a.x + a.y * a.y + a.z * a.z + a.w * a.w;
#pragma unroll
    for (int m = 1; m < 32; m <<= 1) { s += __shfl_xor(s, m); ss += __shfl_xor(ss, m); }
    float mu   = s * (1.0f / E_DIM);
    float var  = ss * (1.0f / E_DIM) - mu * mu;
    float rstd = rsqrtf(var + EPS_F);
    float dotxg = a.x * gv.x + a.y * gv.y + a.z * gv.z + a.w * gv.w;
    float p = (dotxg - mu * sg) * rstd + sb;      // pooled (sum-of-4) value
    // dense store: rows r0+2i (+half), 64 consecutive floats across the wave
    pt[(size_t)(2 * i) * COMP_DIM_C + lane] = p;  // (2i+half)*32 + g == 2i*32 + lane
  }
}

// --- Kernel B: gather W + scatter pooled into LDS agg; atomic flush to Agg.
// 1024 blocks x 256 thr (4 waves); block covers 128 rows; wave 32 rows as
// 16 iterations of 2 rows (lane: row=half, d=lane&31).
__global__ __launch_bounds__(256, 4) void scatter_kernel(
    const float* __restrict__ pooled, const int* __restrict__ node_idx,
    const unsigned short* __restrict__ W16, float* __restrict__ Agg) {
  __shared__ float sagg[D2];  // 8 KB
  const int t     = blockIdx.x >> 6;            // /64
  const int chunk = blockIdx.x & 63;
  const int lane  = threadIdx.x & 63;
  const int wave  = threadIdx.x >> 6;
  const int d     = lane & 31;
  const int half  = lane >> 5;

#pragma unroll
  for (int u = 0; u < 2; ++u)
    reinterpret_cast<float4*>(sagg)[threadIdx.x + u * 256] = make_float4(0.f, 0.f, 0.f, 0.f);
  __syncthreads();

  const int*   nit = node_idx + (size_t)t * N_NODE_C;
  const float* pt  = pooled + (size_t)t * N_NODE_C * COMP_DIM_C;
  const int r0 = chunk * 128 + wave * 32;

  // node ids for all 16 iterations upfront (broadcast loads, breaks dep chain)
  int nr[16];
#pragma unroll
  for (int i = 0; i < 16; ++i) nr[i] = nit[r0 + 2 * i + half];

  for (int ib = 0; ib < 16; ib += 4) {   // 4-deep pipelined W-gather + pooled loads
    unsigned cw[4]; float p[4];
#pragma unroll
    for (int u = 0; u < 4; ++u) {
      cw[u] = W16[(size_t)nr[ib + u] * 32 + d];                       // 64B/row dense
      p[u]  = pt[(size_t)(r0 + 2 * (ib + u) + half) * COMP_DIM_C + d]; // 128B/row dense
    }
#pragma unroll
    for (int u = 0; u < 4; ++u) {
      unsigned long long b = __ballot(cw[u] != 0);
      unsigned ms = (unsigned)(b >> (half * 32));   // alive c-pairs for this row
      while (ms) {
        int j = __builtin_ctz(ms); ms &= ms - 1;
        unsigned w2 = (unsigned)__shfl((int)cw[u], half * 32 + j);
        float pv = p[u];
        unsigned wlo = w2 & 0xFFu, whi = (w2 >> 8) & 0xFFu;
        if (wlo) atomicAdd(&sagg[(2 * j) * COMP_DIM_C + d], pv * (float)wlo);
        if (whi) atomicAdd(&sagg[(2 * j + 1) * COMP_DIM_C + d], pv * (float)whi);
      }
    }
  }

  __syncthreads();
  float* aggt = Agg + (size_t)t * D2;
  for (int k = threadIdx.x; k < D2; k += 256) atomicAdd(&aggt[k], sagg[k]);
}

// --- Final LN over 2048 per t (reads 128KB). 16 WGs.
__global__ __launch_bounds__(256) void final_ln_kernel(
    const float* __restrict__ Agg, const float* __restrict__ g2,
    const float* __restrict__ b2, float* __restrict__ out) {
  const float scale = 1.0f / (4.0f * (float)MAX_LEN_C);
  __shared__ float red[16];
  const int t   = blockIdx.x;
  const int tid = threadIdx.x;
  float y[8];
  float s = 0.0f, ss = 0.0f;
#pragma unroll
  for (int k = 0; k < 8; ++k) {
    float v = Agg[(size_t)t * D2 + tid * 8 + k] * scale;
    y[k] = v; s += v; ss += v * v;
  }
#pragma unroll
  for (int m = 1; m < 64; m <<= 1) { s += __shfl_xor(s, m); ss += __shfl_xor(ss, m); }
  const int w = tid >> 6, ln = tid & 63;
  if (ln == 0) { red[w] = s; red[8 + w] = ss; }
  __syncthreads();
  float ts  = red[0] + red[1] + red[2] + red[3];
  float tss = red[8] + red[9] + red[10] + red[11];
  float mu   = ts * (1.0f / D2);
  float var  = tss * (1.0f / D2) - mu * mu;
  float rstd = rsqrtf(var + EPS_F);
#pragma unroll
  for (int k = 0; k < 8; ++k) {
    int idx = tid * 8 + k;
    out[(size_t)t * D2 + idx] = (y[k] - mu) * rstd * g2[idx] + b2[idx];
  }
}

extern "C" void kernel_launch(void* const* d_in, const int* in_sizes, int n_in,
                              void* d_out, int out_size, void* d_ws, size_t ws_size,
                              hipStream_t stream) {
  const float* x     = (const float*)d_in[0];
  const float* ln1_g = (const float*)d_in[1];
  const float* ln1_b = (const float*)d_in[2];
  const float* ln2_g = (const float*)d_in[3];
  const float* ln2_b = (const float*)d_in[4];
  const int* node_idx = (const int*)d_in[5];
  const int* sidx     = (const int*)d_in[6];
  float* out = (float*)d_out;

  unsigned char* ws = (unsigned char*)d_ws;
  unsigned* W8w = (unsigned*)ws;
  float* Agg    = (float*)(ws + AGG_OFF);
  float* pooled = (float*)(ws + POOL_OFF);  // 16MB, fully overwritten each call

  hipMemsetAsync(ws, 0, ZERO_BYTES, stream);  // W8 + Agg
  build_w8_kernel<<<COMP_LEN_C * 4, 256, 0, stream>>>(sidx, W8w);
  stream_ln_pool<<<T_DIM * 128, 256, 0, stream>>>(x, ln1_g, ln1_b, pooled);
  scatter_kernel<<<T_DIM * 64, 256, 0, stream>>>(pooled, node_idx,
                                                 (const unsigned short*)W8w, Agg);
  final_ln_kernel<<<T_DIM, 256, 0, stream>>>(Agg, ln2_g, ln2_b, out);
}